// Round 2
// baseline (2138.989 us; speedup 1.0000x reference)
//
#include <hip/hip_runtime.h>

typedef unsigned short u16;
typedef __attribute__((ext_vector_type(8))) short short8;
typedef __attribute__((ext_vector_type(4))) float f32x4;

__device__ __forceinline__ u16 f32_to_bf16(float f) {
  unsigned u = __float_as_uint(f);
  u += 0x7fffu + ((u >> 16) & 1u);
  return (u16)(u >> 16);
}
__device__ __forceinline__ float bf16_to_f32(u16 h) {
  return __uint_as_float(((unsigned)h) << 16);
}

// ---------------- weight f32 -> bf16 conversion ----------------
__global__ __launch_bounds__(256) void cvt_f32_bf16(const float* __restrict__ src,
                                                    u16* __restrict__ dst, int n4) {
  int i = blockIdx.x * 256 + threadIdx.x;
  if (i >= n4) return;
  float4 v = ((const float4*)src)[i];
  uint2 r;
  r.x = (unsigned)f32_to_bf16(v.x) | ((unsigned)f32_to_bf16(v.y) << 16);
  r.y = (unsigned)f32_to_bf16(v.z) | ((unsigned)f32_to_bf16(v.w) << 16);
  ((uint2*)dst)[i] = r;
}

// ---------------- GroupNorm: x[B,512,4096] f32 -> h bf16 ----------------
// one block per (b, g); group = 16 channels x 4096 = 65536 elems
__global__ __launch_bounds__(256) void groupnorm_kernel(const float* __restrict__ x,
                                                        const float* __restrict__ gw,
                                                        const float* __restrict__ gb,
                                                        u16* __restrict__ h) {
  int bg = blockIdx.x;
  int bb = bg >> 5, g = bg & 31;
  const float* xp = x + ((long)bb * 512 + g * 16) * 4096;
  u16* hp = h + ((long)bb * 512 + g * 16) * 4096;
  int t = threadIdx.x;
  float s = 0.f, ss = 0.f;
  for (int i = t; i < 16384; i += 256) {  // 16384 float4 = 65536 f32
    float4 v = ((const float4*)xp)[i];
    s += (v.x + v.y) + (v.z + v.w);
    ss += (v.x * v.x + v.y * v.y) + (v.z * v.z + v.w * v.w);
  }
#pragma unroll
  for (int o = 32; o; o >>= 1) { s += __shfl_xor(s, o); ss += __shfl_xor(ss, o); }
  __shared__ float rs[4], rq[4];
  if ((t & 63) == 0) { rs[t >> 6] = s; rq[t >> 6] = ss; }
  __syncthreads();
  float S = rs[0] + rs[1] + rs[2] + rs[3];
  float Q = rq[0] + rq[1] + rq[2] + rq[3];
  float mean = S * (1.f / 65536.f);
  float var = Q * (1.f / 65536.f) - mean * mean;
  float rstd = rsqrtf(var + 1e-6f);
  for (int i = t; i < 16384; i += 256) {
    int c = g * 16 + (i >> 10);  // 1024 float4 per channel
    float w = gw[c], b = gb[c];
    float4 v = ((const float4*)xp)[i];
    float a0 = (v.x - mean) * rstd * w + b;
    float a1 = (v.y - mean) * rstd * w + b;
    float a2 = (v.z - mean) * rstd * w + b;
    float a3 = (v.w - mean) * rstd * w + b;
    uint2 r;
    r.x = (unsigned)f32_to_bf16(a0) | ((unsigned)f32_to_bf16(a1) << 16);
    r.y = (unsigned)f32_to_bf16(a2) | ((unsigned)f32_to_bf16(a3) << 16);
    ((uint2*)hp)[i] = r;
  }
}

// ---------------- generic 64x64 tiled bf16 MFMA GEMM ----------------
// C[m][n] = sum_k A[m][k]*B[k][n]  (per batch blockIdx.z)
// A_T: A stored [K][M] (elem at a[k*lda+m]); else [M][K] (a[m*lda+k])
// B_T: B stored [N][K] (elem at b[n*ldb+k]); else [K][N] (b[k*ldb+n])
// EPI 0: out bf16 = (acc + bias?) * scale
// EPI 1: out f32  = acc + bias + residual
template <bool A_T, bool B_T, int EPI>
__global__ __launch_bounds__(256) void gemm_kernel(
    const u16* __restrict__ Ab, long sA, int lda,
    const u16* __restrict__ Bb, long sB, int ldb,
    void* __restrict__ Cb, long sC, int ldc,
    const float* __restrict__ bias, float scale,
    const float* __restrict__ res, long sR, int K) {
  const u16* A = Ab + (long)blockIdx.z * sA;
  const u16* B = Bb + (long)blockIdx.z * sB;
  const int m0 = blockIdx.y * 64, n0 = blockIdx.x * 64;
  const int t = threadIdx.x;
  const int wave = t >> 6, lane = t & 63;
  const int lrow = lane & 15, q = lane >> 4;
  __shared__ u16 As[64 * 40];  // [m][k], stride 40 (pad 8) keeps 16B align
  __shared__ u16 Bs[64 * 40];  // [n][k]
  f32x4 acc[4] = {};
  for (int k0 = 0; k0 < K; k0 += 32) {
    if (!A_T) {
      const int r = t >> 2, kk = (t & 3) << 3;
      int4 v = *(const int4*)(A + (long)(m0 + r) * lda + (k0 + kk));
      *(int4*)(&As[r * 40 + kk]) = v;
    } else {
      const int kr = t >> 3, mm = (t & 7) << 3;
      int4 v = *(const int4*)(A + (long)(k0 + kr) * lda + (m0 + mm));
      const u16* pv = (const u16*)&v;
#pragma unroll
      for (int j = 0; j < 8; ++j) As[(mm + j) * 40 + kr] = pv[j];
    }
    if (!B_T) {
      const int kr = t >> 3, nn = (t & 7) << 3;
      int4 v = *(const int4*)(B + (long)(k0 + kr) * ldb + (n0 + nn));
      const u16* pv = (const u16*)&v;
#pragma unroll
      for (int j = 0; j < 8; ++j) Bs[(nn + j) * 40 + kr] = pv[j];
    } else {
      const int n = t >> 2, kk = (t & 3) << 3;
      int4 v = *(const int4*)(B + (long)(n0 + n) * ldb + (k0 + kk));
      *(int4*)(&Bs[n * 40 + kk]) = v;
    }
    __syncthreads();
    short8 bf = *(const short8*)(&Bs[(wave * 16 + lrow) * 40 + q * 8]);
#pragma unroll
    for (int fi = 0; fi < 4; ++fi) {
      short8 af = *(const short8*)(&As[(fi * 16 + lrow) * 40 + q * 8]);
      acc[fi] = __builtin_amdgcn_mfma_f32_16x16x32_bf16(af, bf, acc[fi], 0, 0, 0);
    }
    __syncthreads();
  }
  // epilogue: D col=lane&15, row=(lane>>4)*4+reg (+16*fi)
  const int nc = n0 + wave * 16 + lrow;
#pragma unroll
  for (int fi = 0; fi < 4; ++fi) {
#pragma unroll
    for (int r = 0; r < 4; ++r) {
      const int mr = m0 + fi * 16 + q * 4 + r;
      float vv = acc[fi][r];
      if (bias) vv += bias[mr];
      vv *= scale;
      long off = (long)blockIdx.z * sC + (long)mr * ldc + nc;
      if (EPI == 0) {
        ((u16*)Cb)[off] = f32_to_bf16(vv);
      } else {
        const float* R = res + (long)blockIdx.z * sR;
        ((float*)Cb)[off] = vv + R[(long)mr * ldc + nc];
      }
    }
  }
}

// ---------------- row softmax, in place on bf16 [4096 rows x 4096] ----------------
__global__ __launch_bounds__(256) void softmax_kernel(u16* __restrict__ P) {
  long row = blockIdx.x;
  u16* pr = P + row * 4096;
  int t = threadIdx.x;
  int lane = t & 63, wave = t >> 6;
  int4 d0 = ((const int4*)pr)[t];
  int4 d1 = ((const int4*)pr)[t + 256];
  const u16* p0 = (const u16*)&d0;
  const u16* p1 = (const u16*)&d1;
  float v[16];
#pragma unroll
  for (int j = 0; j < 8; ++j) { v[j] = bf16_to_f32(p0[j]); v[8 + j] = bf16_to_f32(p1[j]); }
  float mx = v[0];
#pragma unroll
  for (int j = 1; j < 16; ++j) mx = fmaxf(mx, v[j]);
#pragma unroll
  for (int o = 32; o; o >>= 1) mx = fmaxf(mx, __shfl_xor(mx, o));
  __shared__ float sm[4];
  __shared__ float ssum[4];
  if (lane == 0) sm[wave] = mx;
  __syncthreads();
  mx = fmaxf(fmaxf(sm[0], sm[1]), fmaxf(sm[2], sm[3]));
  float s = 0.f;
#pragma unroll
  for (int j = 0; j < 16; ++j) { v[j] = __expf(v[j] - mx); s += v[j]; }
#pragma unroll
  for (int o = 32; o; o >>= 1) s += __shfl_xor(s, o);
  if (lane == 0) ssum[wave] = s;
  __syncthreads();
  s = ssum[0] + ssum[1] + ssum[2] + ssum[3];
  float inv = 1.0f / s;
  unsigned r0[4], r1[4];
#pragma unroll
  for (int j = 0; j < 4; ++j) {
    r0[j] = (unsigned)f32_to_bf16(v[2 * j] * inv) | ((unsigned)f32_to_bf16(v[2 * j + 1] * inv) << 16);
    r1[j] = (unsigned)f32_to_bf16(v[8 + 2 * j] * inv) | ((unsigned)f32_to_bf16(v[8 + 2 * j + 1] * inv) << 16);
  }
  ((int4*)pr)[t] = *(int4*)r0;
  ((int4*)pr)[t + 256] = *(int4*)r1;
}

extern "C" void kernel_launch(void* const* d_in, const int* in_sizes, int n_in,
                              void* d_out, int out_size, void* d_ws, size_t ws_size,
                              hipStream_t stream) {
  const float* x = (const float*)d_in[0];
  const float* gn_w = (const float*)d_in[1];
  const float* gn_b = (const float*)d_in[2];
  const float* q_w = (const float*)d_in[3];
  const float* q_b = (const float*)d_in[4];
  const float* k_w = (const float*)d_in[5];
  const float* k_b = (const float*)d_in[6];
  const float* v_w = (const float*)d_in[7];
  const float* v_b = (const float*)d_in[8];
  const float* p_w = (const float*)d_in[9];
  const float* p_b = (const float*)d_in[10];

  char* ws = (char*)d_ws;
  const size_t MB = 1ull << 20;
  // ws layout (98 MB total):
  u16* wqb = (u16*)(ws + 0);             // 512 KB each
  u16* wkb = (u16*)(ws + 512 * 1024);
  u16* wvb = (u16*)(ws + 1 * MB);
  u16* wpb = (u16*)(ws + 3 * MB / 2);
  u16* hb = (u16*)(ws + 2 * MB);         // 32 MB (h; later reused as o)
  u16* vb = (u16*)(ws + 34 * MB);        // 32 MB
  u16* Pb = (u16*)(ws + 66 * MB);        // 32 MB per-batch scores
  // d_out doubles as scratch for bf16 q and k (dead before final proj GEMM)
  u16* qb = (u16*)d_out;                 // 32 MB
  u16* kb = (u16*)d_out + 512L * 4096 * 8;  // 32 MB
  u16* ob = hb;                          // o reuses h's storage

  cvt_f32_bf16<<<256, 256, 0, stream>>>(q_w, wqb, 65536);
  cvt_f32_bf16<<<256, 256, 0, stream>>>(k_w, wkb, 65536);
  cvt_f32_bf16<<<256, 256, 0, stream>>>(v_w, wvb, 65536);
  cvt_f32_bf16<<<256, 256, 0, stream>>>(p_w, wpb, 65536);
  groupnorm_kernel<<<256, 256, 0, stream>>>(x, gn_w, gn_b, hb);

  const long sCN = 512L * 4096;
  const long sNN = 4096L * 4096;
  const float scale = 0.04419417382415922f;  // 512^-0.5, folded into q

  // q/k/v: [512x512] x [512x4096] per batch
  gemm_kernel<false, false, 0><<<dim3(64, 8, 8), 256, 0, stream>>>(
      wqb, 0, 512, hb, sCN, 4096, qb, sCN, 4096, q_b, scale, nullptr, 0, 512);
  gemm_kernel<false, false, 0><<<dim3(64, 8, 8), 256, 0, stream>>>(
      wkb, 0, 512, hb, sCN, 4096, kb, sCN, 4096, k_b, 1.0f, nullptr, 0, 512);
  gemm_kernel<false, false, 0><<<dim3(64, 8, 8), 256, 0, stream>>>(
      wvb, 0, 512, hb, sCN, 4096, vb, sCN, 4096, v_b, 1.0f, nullptr, 0, 512);

  // attention per batch, reusing one 32 MB score buffer
  for (int b = 0; b < 8; ++b) {
    const u16* qbb = qb + b * sCN;
    const u16* kbb = kb + b * sCN;
    const u16* vbb = vb + b * sCN;
    u16* obb = ob + b * sCN;
    // scores: S[i][j] = sum_c q[c][i] k[c][j]  (A = q as [K][M], B = k as [K][N])
    gemm_kernel<true, false, 0><<<dim3(64, 64, 1), 256, 0, stream>>>(
        qbb, 0, 4096, kbb, 0, 4096, Pb, 0, 4096, nullptr, 1.0f, nullptr, 0, 512);
    softmax_kernel<<<4096, 256, 0, stream>>>(Pb);
    // o[c][i] = sum_j v[c][j] P[i][j]  (A = v [M][K], B = P stored [N][K])
    gemm_kernel<false, true, 0><<<dim3(64, 8, 1), 256, 0, stream>>>(
        vbb, 0, 4096, Pb, 0, 4096, obb, 0, 4096, nullptr, 1.0f, nullptr, 0, 4096);
  }

  // out = proj_w x o + proj_b + x   (f32) — overwrites q/k scratch in d_out
  gemm_kernel<false, false, 1><<<dim3(64, 8, 8), 256, 0, stream>>>(
      wpb, 0, 512, ob, sCN, 4096, (float*)d_out, sCN, 4096, p_b, 1.0f, x, sCN, 512);
}

// Round 4
// 1059.480 us; speedup vs baseline: 2.0189x; 2.0189x over previous
//
#include <hip/hip_runtime.h>

typedef unsigned short u16;
typedef __attribute__((ext_vector_type(8))) short short8;
typedef __attribute__((ext_vector_type(4))) float f32x4;

__device__ __forceinline__ u16 f32_to_bf16(float f) {
  unsigned u = __float_as_uint(f);
  u += 0x7fffu + ((u >> 16) & 1u);
  return (u16)(u >> 16);
}
__device__ __forceinline__ float bf16_to_f32(u16 h) {
  return __uint_as_float(((unsigned)h) << 16);
}

// async global->LDS, 16B per lane; lds dest = wave-uniform base + lane*16
#define GLD_LDS16(gp, lp)                                                  \
  __builtin_amdgcn_global_load_lds(                                        \
      (const __attribute__((address_space(1))) void*)(gp),                 \
      (__attribute__((address_space(3))) void*)(lp), 16, 0, 0)

// ---------------- weight f32 -> bf16 conversion ----------------
__global__ __launch_bounds__(256) void cvt_f32_bf16(const float* __restrict__ src,
                                                    u16* __restrict__ dst, int n4) {
  int i = blockIdx.x * 256 + threadIdx.x;
  if (i >= n4) return;
  float4 v = ((const float4*)src)[i];
  uint2 r;
  r.x = (unsigned)f32_to_bf16(v.x) | ((unsigned)f32_to_bf16(v.y) << 16);
  r.y = (unsigned)f32_to_bf16(v.z) | ((unsigned)f32_to_bf16(v.w) << 16);
  ((uint2*)dst)[i] = r;
}

// ---------------- GroupNorm -> transposed bf16 hT[B][4096][512] ----------------
// one block per (b, g); group = 16 channels x 4096
__global__ __launch_bounds__(256) void groupnorm_t_kernel(const float* __restrict__ x,
                                                          const float* __restrict__ gw,
                                                          const float* __restrict__ gb,
                                                          u16* __restrict__ hT) {
  int bg = blockIdx.x;
  int bb = bg >> 5, g = bg & 31;
  const float* xp = x + ((long)bb * 512 + g * 16) * 4096;
  int t = threadIdx.x;
  float s = 0.f, ss = 0.f;
  for (int i = t; i < 16384; i += 256) {  // 16384 float4 = 65536 f32
    float4 v = ((const float4*)xp)[i];
    s += (v.x + v.y) + (v.z + v.w);
    ss += (v.x * v.x + v.y * v.y) + (v.z * v.z + v.w * v.w);
  }
#pragma unroll
  for (int o = 32; o; o >>= 1) { s += __shfl_xor(s, o); ss += __shfl_xor(ss, o); }
  __shared__ float rs[4], rq[4];
  if ((t & 63) == 0) { rs[t >> 6] = s; rq[t >> 6] = ss; }
  __syncthreads();
  float S = rs[0] + rs[1] + rs[2] + rs[3];
  float Q = rq[0] + rq[1] + rq[2] + rq[3];
  float mean = S * (1.f / 65536.f);
  float var = Q * (1.f / 65536.f) - mean * mean;
  float rstd = rsqrtf(var + 1e-6f);
  float wv[16], bv[16];
#pragma unroll
  for (int c = 0; c < 16; ++c) { wv[c] = gw[g * 16 + c] * rstd; bv[c] = gb[g * 16 + c]; }
  u16* hp = hT + (long)bb * 4096 * 512 + g * 16;
  for (int i0 = 0; i0 < 4096; i0 += 256) {
    int i = i0 + t;
    u16 o[16];
#pragma unroll
    for (int c = 0; c < 16; ++c) {
      float v = xp[c * 4096 + i];  // coalesced across lanes
      o[c] = f32_to_bf16((v - mean) * wv[c] + bv[c]);
    }
    *(int4*)(hp + (long)i * 512) = *(int4*)(o);
    *(int4*)(hp + (long)i * 512 + 8) = *(int4*)(o + 8);
  }
}

// ---------------- m97-style 128x128 bf16 MFMA GEMM (B^T form) ----------------
// C[m][n] = sum_k A[m][k] * B[n][k], K % 32 == 0, M/N tiles of 128.
// grid: x = N/128, y = M/128, z = batch. EPI 0: bf16 out; EPI 1: f32 out + residual.
template <int EPI>
__global__ __launch_bounds__(256) void gemm128(
    const u16* __restrict__ Ab, long sA, int lda,
    const u16* __restrict__ Bb, long sB, int ldb,
    void* __restrict__ Cb, long sC, int ldc,
    const float* __restrict__ biasM, const float* __restrict__ biasN,
    float scale, const float* __restrict__ res, long sR, int K) {
  const u16* A = Ab + (long)blockIdx.z * sA;
  const u16* B = Bb + (long)blockIdx.z * sB;
  const int m0 = blockIdx.y * 128, n0 = blockIdx.x * 128;
  const int t = threadIdx.x;
  const int wave = t >> 6, lane = t & 63;
  const int wy = wave >> 1, wx = wave & 1;
  const int lr = lane & 15, q = lane >> 4;
  __shared__ __align__(16) u16 As[128 * 32];  // [m][k] row-major, no pad (DMA layout)
  __shared__ __align__(16) u16 Bs[128 * 32];  // [n][k] row-major, no pad
  f32x4 acc[4][4] = {};
  // staging: tile = 8192 B = 512 chunks of 16 B; chunk = c*256 + t
  // row = chunk>>2 (32 u16/row = 4 chunks), ko = (chunk&3)*8
  // LDS dest (c*256 + wave*64)*16 B is wave-uniform; lane scatter = +lane*16
  for (int k0 = 0; k0 < K; k0 += 32) {
#pragma unroll
    for (int c = 0; c < 2; ++c) {
      const int chunk = c * 256 + t;
      const int row = chunk >> 2, ko = (chunk & 3) << 3;
      const int ldsoff = (c * 256 + wave * 64) * 8;  // u16 units
      GLD_LDS16(A + (long)(m0 + row) * lda + (k0 + ko), As + ldsoff);
      GLD_LDS16(B + (long)(n0 + row) * ldb + (k0 + ko), Bs + ldsoff);
    }
    __syncthreads();  // drains vmcnt before ds_read
    short8 af[4], bf[4];
#pragma unroll
    for (int i = 0; i < 4; ++i)
      af[i] = *(const short8*)(&As[(wy * 64 + i * 16 + lr) * 32 + q * 8]);
#pragma unroll
    for (int j = 0; j < 4; ++j)
      bf[j] = *(const short8*)(&Bs[(wx * 64 + j * 16 + lr) * 32 + q * 8]);
#pragma unroll
    for (int i = 0; i < 4; ++i)
#pragma unroll
      for (int j = 0; j < 4; ++j)
        acc[i][j] = __builtin_amdgcn_mfma_f32_16x16x32_bf16(af[i], bf[j], acc[i][j], 0, 0, 0);
    __syncthreads();
  }
  // epilogue: frag D col=lane&15, row=(lane>>4)*4+r
#pragma unroll
  for (int i = 0; i < 4; ++i) {
#pragma unroll
    for (int r = 0; r < 4; ++r) {
      const int mr = m0 + wy * 64 + i * 16 + q * 4 + r;
      const float bm = biasM ? biasM[mr] : 0.f;
#pragma unroll
      for (int j = 0; j < 4; ++j) {
        const int nc = n0 + wx * 64 + j * 16 + lr;
        float vv = acc[i][j][r] + bm;
        if (biasN) vv += biasN[nc];
        vv *= scale;
        const long off = (long)blockIdx.z * sC + (long)mr * ldc + nc;
        if (EPI == 0) {
          ((u16*)Cb)[off] = f32_to_bf16(vv);
        } else {
          ((float*)Cb)[off] = vv + res[(long)blockIdx.z * sR + (long)mr * ldc + nc];
        }
      }
    }
  }
}

// ---------------- row softmax, in place on bf16 [4096 x 4096] per batch ----------------
__global__ __launch_bounds__(256) void softmax_kernel(u16* __restrict__ P) {
  u16* pr = P + (long)blockIdx.y * 4096 * 4096 + (long)blockIdx.x * 4096;
  int t = threadIdx.x;
  int lane = t & 63, wave = t >> 6;
  int4 d0 = ((const int4*)pr)[t];
  int4 d1 = ((const int4*)pr)[t + 256];
  const u16* p0 = (const u16*)&d0;
  const u16* p1 = (const u16*)&d1;
  float v[16];
#pragma unroll
  for (int j = 0; j < 8; ++j) { v[j] = bf16_to_f32(p0[j]); v[8 + j] = bf16_to_f32(p1[j]); }
  float mx = v[0];
#pragma unroll
  for (int j = 1; j < 16; ++j) mx = fmaxf(mx, v[j]);
#pragma unroll
  for (int o = 32; o; o >>= 1) mx = fmaxf(mx, __shfl_xor(mx, o));
  __shared__ float sm[4];
  __shared__ float ssum[4];
  if (lane == 0) sm[wave] = mx;
  __syncthreads();
  mx = fmaxf(fmaxf(sm[0], sm[1]), fmaxf(sm[2], sm[3]));
  float s = 0.f;
#pragma unroll
  for (int j = 0; j < 16; ++j) { v[j] = __expf(v[j] - mx); s += v[j]; }
#pragma unroll
  for (int o = 32; o; o >>= 1) s += __shfl_xor(s, o);
  if (lane == 0) ssum[wave] = s;
  __syncthreads();
  s = ssum[0] + ssum[1] + ssum[2] + ssum[3];
  float inv = 1.0f / s;
  unsigned r0[4], r1[4];
#pragma unroll
  for (int j = 0; j < 4; ++j) {
    r0[j] = (unsigned)f32_to_bf16(v[2 * j] * inv) | ((unsigned)f32_to_bf16(v[2 * j + 1] * inv) << 16);
    r1[j] = (unsigned)f32_to_bf16(v[8 + 2 * j] * inv) | ((unsigned)f32_to_bf16(v[8 + 2 * j + 1] * inv) << 16);
  }
  ((int4*)pr)[t] = *(int4*)r0;
  ((int4*)pr)[t + 256] = *(int4*)r1;
}

extern "C" void kernel_launch(void* const* d_in, const int* in_sizes, int n_in,
                              void* d_out, int out_size, void* d_ws, size_t ws_size,
                              hipStream_t stream) {
  const float* x = (const float*)d_in[0];
  const float* gn_w = (const float*)d_in[1];
  const float* gn_b = (const float*)d_in[2];
  const float* q_w = (const float*)d_in[3];
  const float* q_b = (const float*)d_in[4];
  const float* k_w = (const float*)d_in[5];
  const float* k_b = (const float*)d_in[6];
  const float* v_w = (const float*)d_in[7];
  const float* v_b = (const float*)d_in[8];
  const float* p_w = (const float*)d_in[9];
  const float* p_b = (const float*)d_in[10];

  char* ws = (char*)d_ws;
  const size_t MB = 1ull << 20;
  u16* wqb = (u16*)(ws + 0);              // 512 KB each
  u16* wkb = (u16*)(ws + 512 * 1024);
  u16* wvb = (u16*)(ws + 1 * MB);
  u16* wpb = (u16*)(ws + 3 * MB / 2);
  u16* hb = (u16*)(ws + 2 * MB);          // 32 MB: hT, later reused as oT
  u16* vb = (u16*)(ws + 34 * MB);         // 32 MB: v [C][N]
  u16* Pb = (u16*)(ws + 66 * MB);         // 32*NB MB: score groups
  u16* qb = (u16*)d_out;                  // 32 MB scratch (dead before proj)
  u16* kb = (u16*)d_out + 512L * 4096 * 8;
  u16* ob = hb;

  // batches per attention group, sized by available workspace
  int NB = 1;
  if (ws_size >= 66 * MB + 8 * 32 * MB) NB = 8;
  else if (ws_size >= 66 * MB + 4 * 32 * MB) NB = 4;
  else if (ws_size >= 66 * MB + 2 * 32 * MB) NB = 2;

  cvt_f32_bf16<<<256, 256, 0, stream>>>(q_w, wqb, 65536);
  cvt_f32_bf16<<<256, 256, 0, stream>>>(k_w, wkb, 65536);
  cvt_f32_bf16<<<256, 256, 0, stream>>>(v_w, wvb, 65536);
  cvt_f32_bf16<<<256, 256, 0, stream>>>(p_w, wpb, 65536);
  groupnorm_t_kernel<<<256, 256, 0, stream>>>(x, gn_w, gn_b, hb);

  const long sCN = 512L * 4096;
  const long sNN = 4096L * 4096;
  const float scale = 0.04419417382415922f;  // 512^-0.5, folded into q

  // qT[i][c'] = sum_c hT[i][c] qw[c'][c]; M=4096 N=512 K=512
  gemm128<0><<<dim3(4, 32, 8), 256, 0, stream>>>(
      hb, sCN, 512, wqb, 0, 512, qb, sCN, 512, nullptr, q_b, scale, nullptr, 0, 512);
  gemm128<0><<<dim3(4, 32, 8), 256, 0, stream>>>(
      hb, sCN, 512, wkb, 0, 512, kb, sCN, 512, nullptr, k_b, 1.0f, nullptr, 0, 512);
  // v[c'][j] = sum_c vw[c'][c] hT[j][c]; M=512 N=4096 K=512
  gemm128<0><<<dim3(32, 4, 8), 256, 0, stream>>>(
      wvb, 0, 512, hb, sCN, 512, vb, sCN, 4096, v_b, nullptr, 1.0f, nullptr, 0, 512);

  for (int b0 = 0; b0 < 8; b0 += NB) {
    // S[i][j] = sum_c qT[i][c] kT[j][c]; M=N=4096 K=512
    gemm128<0><<<dim3(32, 32, NB), 256, 0, stream>>>(
        qb + b0 * sCN, sCN, 512, kb + b0 * sCN, sCN, 512, Pb, sNN, 4096,
        nullptr, nullptr, 1.0f, nullptr, 0, 512);
    softmax_kernel<<<dim3(4096, NB), 256, 0, stream>>>(Pb);
    // oT[i][c'] = sum_j P[i][j] v[c'][j]; M=4096 N=512 K=4096
    gemm128<0><<<dim3(4, 32, NB), 256, 0, stream>>>(
        Pb, sNN, 4096, vb + b0 * sCN, sCN, 4096, ob + b0 * sCN, sCN, 512,
        nullptr, nullptr, 1.0f, nullptr, 0, 4096);
  }

  // out[c'][i] = sum_d pw[c'][d] oT[i][d] + pb[c'] + x; M=512 N=4096 K=512, f32
  gemm128<1><<<dim3(32, 4, 8), 256, 0, stream>>>(
      wpb, 0, 512, ob, sCN, 512, (float*)d_out, sCN, 4096, p_b, nullptr, 1.0f,
      x, sCN, 512);
}

// Round 5
// 971.457 us; speedup vs baseline: 2.2018x; 1.0906x over previous
//
#include <hip/hip_runtime.h>

typedef unsigned short u16;
typedef __attribute__((ext_vector_type(8))) short short8;
typedef __attribute__((ext_vector_type(4))) float f32x4;

__device__ __forceinline__ u16 f32_to_bf16(float f) {
  unsigned u = __float_as_uint(f);
  u += 0x7fffu + ((u >> 16) & 1u);
  return (u16)(u >> 16);
}
__device__ __forceinline__ float bf16_to_f32(u16 h) {
  return __uint_as_float(((unsigned)h) << 16);
}

// async global->LDS, 16B per lane; lds dest = wave-uniform base + lane*16
#define GLD_LDS16(gp, lp)                                                  \
  __builtin_amdgcn_global_load_lds(                                        \
      (const __attribute__((address_space(1))) void*)(gp),                 \
      (__attribute__((address_space(3))) void*)(lp), 16, 0, 0)

// ---------------- fused 4-weight f32 -> bf16 conversion ----------------
__global__ __launch_bounds__(256) void cvt4_f32_bf16(const float* __restrict__ s0,
                                                     const float* __restrict__ s1,
                                                     const float* __restrict__ s2,
                                                     const float* __restrict__ s3,
                                                     u16* __restrict__ d0,
                                                     u16* __restrict__ d1,
                                                     u16* __restrict__ d2,
                                                     u16* __restrict__ d3) {
  const float* s = blockIdx.y == 0 ? s0 : blockIdx.y == 1 ? s1 : blockIdx.y == 2 ? s2 : s3;
  u16* d = blockIdx.y == 0 ? d0 : blockIdx.y == 1 ? d1 : blockIdx.y == 2 ? d2 : d3;
  int i = blockIdx.x * 256 + threadIdx.x;  // 65536 float4 per tensor
  float4 v = ((const float4*)s)[i];
  uint2 r;
  r.x = (unsigned)f32_to_bf16(v.x) | ((unsigned)f32_to_bf16(v.y) << 16);
  r.y = (unsigned)f32_to_bf16(v.z) | ((unsigned)f32_to_bf16(v.w) << 16);
  ((uint2*)d)[i] = r;
}

// ---------------- GroupNorm stats: mean/rstd per (b,g) ----------------
// grid 256 = (b*32+g), 1024 threads; group data is contiguous 65536 f32
__global__ __launch_bounds__(1024) void gn_stats(const float* __restrict__ x,
                                                 float2* __restrict__ stats) {
  int bg = blockIdx.x;
  const float* xp = x + (long)bg * 65536;
  int t = threadIdx.x;
  float s = 0.f, ss = 0.f;
  for (int i = t; i < 16384; i += 1024) {
    float4 v = ((const float4*)xp)[i];
    s += (v.x + v.y) + (v.z + v.w);
    ss += (v.x * v.x + v.y * v.y) + (v.z * v.z + v.w * v.w);
  }
#pragma unroll
  for (int o = 32; o; o >>= 1) { s += __shfl_xor(s, o); ss += __shfl_xor(ss, o); }
  __shared__ float rs[16], rq[16];
  int wave = t >> 6, lane = t & 63;
  if (lane == 0) { rs[wave] = s; rq[wave] = ss; }
  __syncthreads();
  if (wave == 0) {
    float a = lane < 16 ? rs[lane] : 0.f;
    float b = lane < 16 ? rq[lane] : 0.f;
#pragma unroll
    for (int o = 8; o; o >>= 1) { a += __shfl_xor(a, o); b += __shfl_xor(b, o); }
    if (lane == 0) {
      float mean = a * (1.f / 65536.f);
      float var = b * (1.f / 65536.f) - mean * mean;
      stats[bg] = make_float2(mean, rsqrtf(var + 1e-6f));
    }
  }
}

// ---------------- GroupNorm apply + transpose -> hT[B][4096][512] ----------------
// grid (4 chunks, 32 g, 8 b), 256 threads; block: 16 ch x 1024 positions
__global__ __launch_bounds__(256) void gn_apply_t(const float* __restrict__ x,
                                                  const float* __restrict__ gw,
                                                  const float* __restrict__ gb,
                                                  const float2* __restrict__ stats,
                                                  u16* __restrict__ hT) {
  const int g = blockIdx.y, bb = blockIdx.z;
  const float2 st = stats[bb * 32 + g];
  const float mean = st.x, rstd = st.y;
  const float* xp = x + ((long)bb * 512 + g * 16) * 4096;
  u16* hp = hT + (long)bb * 4096 * 512 + g * 16;
  const int i = blockIdx.x * 1024 + threadIdx.x * 4;
#pragma unroll
  for (int half = 0; half < 2; ++half) {
    float w[8], bv[8];
#pragma unroll
    for (int c = 0; c < 8; ++c) {
      w[c] = gw[g * 16 + half * 8 + c] * rstd;
      bv[c] = gb[g * 16 + half * 8 + c];
    }
    float v[8][4];
#pragma unroll
    for (int c = 0; c < 8; ++c) {
      float4 f = *(const float4*)(xp + (long)(half * 8 + c) * 4096 + i);
      v[c][0] = f.x; v[c][1] = f.y; v[c][2] = f.z; v[c][3] = f.w;
    }
#pragma unroll
    for (int p = 0; p < 4; ++p) {
      u16 o[8];
#pragma unroll
      for (int c = 0; c < 8; ++c) o[c] = f32_to_bf16((v[c][p] - mean) * w[c] + bv[c]);
      *(int4*)(hp + (long)(i + p) * 512 + half * 8) = *(int4*)o;
    }
  }
}

// ---------------- m97-style 128x128 bf16 MFMA GEMM (B^T form) ----------------
// C[m][n] = sum_k A[m][k] * B[n][k], K % 32 == 0, M/N tiles of 128.
// grid: x = N/128, y = M/128, z = batch. EPI 0: bf16 out; EPI 1: f32 out + residual.
template <int EPI>
__global__ __launch_bounds__(256) void gemm128(
    const u16* __restrict__ Ab, long sA, int lda,
    const u16* __restrict__ Bb, long sB, int ldb,
    void* __restrict__ Cb, long sC, int ldc,
    const float* __restrict__ biasM, const float* __restrict__ biasN,
    float scale, const float* __restrict__ res, long sR, int K) {
  const u16* A = Ab + (long)blockIdx.z * sA;
  const u16* B = Bb + (long)blockIdx.z * sB;
  const int m0 = blockIdx.y * 128, n0 = blockIdx.x * 128;
  const int t = threadIdx.x;
  const int wave = t >> 6, lane = t & 63;
  const int wy = wave >> 1, wx = wave & 1;
  const int lr = lane & 15, q = lane >> 4;
  __shared__ __align__(16) u16 As[128 * 32];  // [m][k] row-major, no pad (DMA layout)
  __shared__ __align__(16) u16 Bs[128 * 32];  // [n][k] row-major, no pad
  f32x4 acc[4][4] = {};
  // staging: tile = 8192 B = 512 chunks of 16 B; chunk = c*256 + t
  // row = chunk>>2 (32 u16/row = 4 chunks), ko = (chunk&3)*8
  // LDS dest (c*256 + wave*64)*16 B is wave-uniform; lane scatter = +lane*16
  for (int k0 = 0; k0 < K; k0 += 32) {
#pragma unroll
    for (int c = 0; c < 2; ++c) {
      const int chunk = c * 256 + t;
      const int row = chunk >> 2, ko = (chunk & 3) << 3;
      const int ldsoff = (c * 256 + wave * 64) * 8;  // u16 units
      GLD_LDS16(A + (long)(m0 + row) * lda + (k0 + ko), As + ldsoff);
      GLD_LDS16(B + (long)(n0 + row) * ldb + (k0 + ko), Bs + ldsoff);
    }
    __syncthreads();  // drains vmcnt before ds_read
    short8 af[4], bf[4];
#pragma unroll
    for (int i = 0; i < 4; ++i)
      af[i] = *(const short8*)(&As[(wy * 64 + i * 16 + lr) * 32 + q * 8]);
#pragma unroll
    for (int j = 0; j < 4; ++j)
      bf[j] = *(const short8*)(&Bs[(wx * 64 + j * 16 + lr) * 32 + q * 8]);
#pragma unroll
    for (int i = 0; i < 4; ++i)
#pragma unroll
      for (int j = 0; j < 4; ++j)
        acc[i][j] = __builtin_amdgcn_mfma_f32_16x16x32_bf16(af[i], bf[j], acc[i][j], 0, 0, 0);
    __syncthreads();
  }
  // epilogue: frag D col=lane&15, row=(lane>>4)*4+r
#pragma unroll
  for (int i = 0; i < 4; ++i) {
#pragma unroll
    for (int r = 0; r < 4; ++r) {
      const int mr = m0 + wy * 64 + i * 16 + q * 4 + r;
      const float bm = biasM ? biasM[mr] : 0.f;
#pragma unroll
      for (int j = 0; j < 4; ++j) {
        const int nc = n0 + wx * 64 + j * 16 + lr;
        float vv = acc[i][j][r] + bm;
        if (biasN) vv += biasN[nc];
        vv *= scale;
        const long off = (long)blockIdx.z * sC + (long)mr * ldc + nc;
        if (EPI == 0) {
          ((u16*)Cb)[off] = f32_to_bf16(vv);
        } else {
          ((float*)Cb)[off] = vv + res[(long)blockIdx.z * sR + (long)mr * ldc + nc];
        }
      }
    }
  }
}

// ---------------- row softmax, in place on bf16 [4096 x 4096] per batch ----------------
__global__ __launch_bounds__(256) void softmax_kernel(u16* __restrict__ P) {
  u16* pr = P + (long)blockIdx.y * 4096 * 4096 + (long)blockIdx.x * 4096;
  int t = threadIdx.x;
  int lane = t & 63, wave = t >> 6;
  int4 d0 = ((const int4*)pr)[t];
  int4 d1 = ((const int4*)pr)[t + 256];
  const u16* p0 = (const u16*)&d0;
  const u16* p1 = (const u16*)&d1;
  float v[16];
#pragma unroll
  for (int j = 0; j < 8; ++j) { v[j] = bf16_to_f32(p0[j]); v[8 + j] = bf16_to_f32(p1[j]); }
  float mx = v[0];
#pragma unroll
  for (int j = 1; j < 16; ++j) mx = fmaxf(mx, v[j]);
#pragma unroll
  for (int o = 32; o; o >>= 1) mx = fmaxf(mx, __shfl_xor(mx, o));
  __shared__ float sm[4];
  __shared__ float ssum[4];
  if (lane == 0) sm[wave] = mx;
  __syncthreads();
  mx = fmaxf(fmaxf(sm[0], sm[1]), fmaxf(sm[2], sm[3]));
  float s = 0.f;
#pragma unroll
  for (int j = 0; j < 16; ++j) { v[j] = __expf(v[j] - mx); s += v[j]; }
#pragma unroll
  for (int o = 32; o; o >>= 1) s += __shfl_xor(s, o);
  if (lane == 0) ssum[wave] = s;
  __syncthreads();
  s = ssum[0] + ssum[1] + ssum[2] + ssum[3];
  float inv = 1.0f / s;
  unsigned r0[4], r1[4];
#pragma unroll
  for (int j = 0; j < 4; ++j) {
    r0[j] = (unsigned)f32_to_bf16(v[2 * j] * inv) | ((unsigned)f32_to_bf16(v[2 * j + 1] * inv) << 16);
    r1[j] = (unsigned)f32_to_bf16(v[8 + 2 * j] * inv) | ((unsigned)f32_to_bf16(v[8 + 2 * j + 1] * inv) << 16);
  }
  ((int4*)pr)[t] = *(int4*)r0;
  ((int4*)pr)[t + 256] = *(int4*)r1;
}

extern "C" void kernel_launch(void* const* d_in, const int* in_sizes, int n_in,
                              void* d_out, int out_size, void* d_ws, size_t ws_size,
                              hipStream_t stream) {
  const float* x = (const float*)d_in[0];
  const float* gn_w = (const float*)d_in[1];
  const float* gn_b = (const float*)d_in[2];
  const float* q_w = (const float*)d_in[3];
  const float* q_b = (const float*)d_in[4];
  const float* k_w = (const float*)d_in[5];
  const float* k_b = (const float*)d_in[6];
  const float* v_w = (const float*)d_in[7];
  const float* v_b = (const float*)d_in[8];
  const float* p_w = (const float*)d_in[9];
  const float* p_b = (const float*)d_in[10];

  char* ws = (char*)d_ws;
  const size_t MB = 1ull << 20;
  u16* wqb = (u16*)(ws + 0);              // 512 KB each
  u16* wkb = (u16*)(ws + 512 * 1024);
  u16* wvb = (u16*)(ws + 1 * MB);
  u16* wpb = (u16*)(ws + 3 * MB / 2);
  u16* hb = (u16*)(ws + 2 * MB);          // 32 MB: hT, later reused as oT
  u16* vb = (u16*)(ws + 34 * MB);         // 32 MB: v [C][N]
  u16* Pb = (u16*)(ws + 66 * MB);         // 32*NB MB: score groups
  // stats buffer (4 KB) lives at the start of the P region — temporally
  // disjoint: written/read in the groupnorm phase, P written only later.
  float2* stats = (float2*)(ws + 66 * MB);
  u16* qb = (u16*)d_out;                  // 32 MB scratch (dead before proj)
  u16* kb = (u16*)d_out + 512L * 4096 * 8;
  u16* ob = hb;

  // batches per attention group, sized by available workspace
  int NB = 1;
  if (ws_size >= 66 * MB + 8 * 32 * MB) NB = 8;
  else if (ws_size >= 66 * MB + 4 * 32 * MB) NB = 4;
  else if (ws_size >= 66 * MB + 2 * 32 * MB) NB = 2;

  cvt4_f32_bf16<<<dim3(256, 4), 256, 0, stream>>>(q_w, k_w, v_w, p_w, wqb, wkb, wvb, wpb);
  gn_stats<<<256, 1024, 0, stream>>>(x, stats);
  gn_apply_t<<<dim3(4, 32, 8), 256, 0, stream>>>(x, gn_w, gn_b, stats, hb);

  const long sCN = 512L * 4096;
  const long sNN = 4096L * 4096;
  const float scale = 0.04419417382415922f;  // 512^-0.5, folded into q

  // qT[i][c'] = sum_c hT[i][c] qw[c'][c]; M=4096 N=512 K=512
  gemm128<0><<<dim3(4, 32, 8), 256, 0, stream>>>(
      hb, sCN, 512, wqb, 0, 512, qb, sCN, 512, nullptr, q_b, scale, nullptr, 0, 512);
  gemm128<0><<<dim3(4, 32, 8), 256, 0, stream>>>(
      hb, sCN, 512, wkb, 0, 512, kb, sCN, 512, nullptr, k_b, 1.0f, nullptr, 0, 512);
  // v[c'][j] = sum_c vw[c'][c] hT[j][c]; M=512 N=4096 K=512
  gemm128<0><<<dim3(32, 4, 8), 256, 0, stream>>>(
      wvb, 0, 512, hb, sCN, 512, vb, sCN, 4096, v_b, nullptr, 1.0f, nullptr, 0, 512);

  for (int b0 = 0; b0 < 8; b0 += NB) {
    // S[i][j] = sum_c qT[i][c] kT[j][c]; M=N=4096 K=512
    gemm128<0><<<dim3(32, 32, NB), 256, 0, stream>>>(
        qb + b0 * sCN, sCN, 512, kb + b0 * sCN, sCN, 512, Pb, sNN, 4096,
        nullptr, nullptr, 1.0f, nullptr, 0, 512);
    softmax_kernel<<<dim3(4096, NB), 256, 0, stream>>>(Pb);
    // oT[i][c'] = sum_j P[i][j] v[c'][j]; M=4096 N=512 K=4096
    gemm128<0><<<dim3(4, 32, NB), 256, 0, stream>>>(
        Pb, sNN, 4096, vb + b0 * sCN, sCN, 4096, ob + b0 * sCN, sCN, 512,
        nullptr, nullptr, 1.0f, nullptr, 0, 4096);
  }

  // out[c'][i] = sum_d pw[c'][d] oT[i][d] + pb[c'] + x; M=512 N=4096 K=512, f32
  gemm128<1><<<dim3(32, 4, 8), 256, 0, stream>>>(
      wpb, 0, 512, ob, sCN, 512, (float*)d_out, sCN, 4096, p_b, nullptr, 1.0f,
      x, sCN, 512);
}